// Round 17
// baseline (2286.232 us; speedup 1.0000x reference)
//
#include <hip/hip_runtime.h>
#include <stdint.h>

#define T_STEPS 256
#define BATCH   8192

// Reference semantics (proven by round-16 probe P0, 1M-decision agreement):
//   cur  = sum_k w[k]*s[k] (ascending, single acc) + bias
//   mem' = fmaf(0.95, mem, cur) - reset          (reset from OLD mem, {0,1})
//   spike = mem' > 1.0
__device__ __forceinline__ float lif_update(float mem, float cur) {
#pragma clang fp contract(off)
    float reset = (mem > 1.0f) ? 1.0f : 0.0f;
    return fmaf(0.95f, mem, cur) - reset;
}

__global__ __launch_bounds__(256, 2)
void snn_kernel(const float* __restrict__ left, const float* __restrict__ right,
                const float* __restrict__ ctx,
                const float* __restrict__ Wl1, const float* __restrict__ bl1,
                const float* __restrict__ Wl2, const float* __restrict__ bl2,
                const float* __restrict__ Wr1, const float* __restrict__ br1,
                const float* __restrict__ Wr2, const float* __restrict__ br2,
                const float* __restrict__ Wc,  const float* __restrict__ bc,
                const float* __restrict__ Wf,  const float* __restrict__ bf,
                const float* __restrict__ Wf2, const float* __restrict__ bf2,
                const float* __restrict__ Wo,  const float* __restrict__ bo,
                float* __restrict__ out)
{
    const int lane = threadIdx.x & 63;
    const int b    = blockIdx.x * 4 + (threadIdx.x >> 6);

    const int j32 = lane & 31;
    const int jc  = lane & 15;
    const int jf2 = (lane < 48) ? lane : 47;  // lanes 48-63 shadow, excluded from ballot
    const int n_o = lane >> 4;

    // ---- stage Wo into LDS once (4x48 floats; read-only in hot loop) ----
    __shared__ float wo_s[4 * 48];
    for (int i = threadIdx.x; i < 4 * 48; i += 256) wo_s[i] = Wo[i];
    __syncthreads();

    // ---- preload all other weights into per-lane registers ----
    float w1[6], w2[32], wcr[3], wf[80], wf2r[64];
    const float* W1row = (lane < 32) ? (Wl1 + lane * 6)  : (Wr1 + j32 * 6);
    const float* W2row = (lane < 32) ? (Wl2 + lane * 32) : (Wr2 + j32 * 32);
    const float  b1    = (lane < 32) ? bl1[lane] : br1[j32];
    const float  b2    = (lane < 32) ? bl2[lane] : br2[j32];
#pragma unroll
    for (int k = 0; k < 6;  ++k) w1[k]  = W1row[k];
#pragma unroll
    for (int k = 0; k < 32; ++k) w2[k]  = W2row[k];
#pragma unroll
    for (int k = 0; k < 3;  ++k) wcr[k] = Wc[jc * 3 + k];
    const float bcr = bc[jc];
#pragma unroll
    for (int k = 0; k < 80; ++k) wf[k]  = Wf[lane * 80 + k];
    const float bfr = bf[lane];
#pragma unroll
    for (int k = 0; k < 64; ++k) wf2r[k] = Wf2[jf2 * 64 + k];
    const float bf2r = bf2[jf2];
    const float bor = bo[n_o];

    // ---- membrane state (registers, persists across T) ----
    float ml1 = 0.f, ml2 = 0.f, mc = 0.f, mf = 0.f, mf2 = 0.f, mo = 0.f;

    for (int t = 0; t < T_STEPS; ++t) {
        const size_t base = (size_t)t * BATCH + b;

        // ---- inputs: lanes 0-5 left, 32-37 right, 8-10 ctx -> one ballot ----
        float vin = 0.f;
        if (lane < 6)                     vin = left [base * 6 + lane];
        else if (lane >= 32 && lane < 38) vin = right[base * 6 + (lane - 32)];
        else if (lane >= 8 && lane < 11)  vin = ctx  [base * 3 + (lane - 8)];
        const uint64_t in_mask = __ballot(vin > 0.5f);

        // ---- layer l1 (lanes 0-31) / r1 (lanes 32-63) ----
        {
            const uint32_t m = (lane < 32) ? (uint32_t)in_mask : (uint32_t)(in_mask >> 32);
            float acc = 0.f;
#pragma unroll
            for (int k = 0; k < 6; ++k)
                acc = fmaf(w1[k], (float)((m >> k) & 1u), acc);
            ml1 = lif_update(ml1, acc + b1);
        }
        const uint64_t s1 = __ballot(ml1 > 1.0f);   // lo32 = s_l1, hi32 = s_r1

        // ---- layer l2 / r2 ----
        {
            const uint32_t m = (lane < 32) ? (uint32_t)s1 : (uint32_t)(s1 >> 32);
            float acc = 0.f;
#pragma unroll
            for (int k = 0; k < 32; ++k)
                acc = fmaf(w2[k], (float)((m >> k) & 1u), acc);
            ml2 = lif_update(ml2, acc + b2);
        }
        const uint64_t s2 = __ballot(ml2 > 1.0f);   // lo32 = s_l2, hi32 = s_r2

        // ---- layer c (real state on lanes 0-15; others shadow harmlessly) ----
        {
            const uint32_t m = (uint32_t)(in_mask >> 8) & 0x7u;
            float acc = 0.f;
#pragma unroll
            for (int k = 0; k < 3; ++k)
                acc = fmaf(wcr[k], (float)((m >> k) & 1u), acc);
            mc = lif_update(mc, acc + bcr);
        }
        const uint32_t sc = (uint32_t)__ballot((lane < 16) && (mc > 1.0f));

        // ---- layer f: 64 outputs, fused input = s_l2 | s_r2 | s_c (80 bits) ----
        {
            const uint32_t lo = (uint32_t)s2, hi = (uint32_t)(s2 >> 32);
            float acc = 0.f;
#pragma unroll
            for (int k = 0; k < 32; ++k)
                acc = fmaf(wf[k],      (float)((lo >> k) & 1u), acc);
#pragma unroll
            for (int k = 0; k < 32; ++k)
                acc = fmaf(wf[32 + k], (float)((hi >> k) & 1u), acc);
#pragma unroll
            for (int k = 0; k < 16; ++k)
                acc = fmaf(wf[64 + k], (float)((sc >> k) & 1u), acc);
            mf = lif_update(mf, acc + bfr);
        }
        const uint64_t sf = __ballot(mf > 1.0f);

        // ---- layer f2: 48 outputs on lanes 0-47 ----
        {
            const uint32_t lo = (uint32_t)sf, hi = (uint32_t)(sf >> 32);
            float acc = 0.f;
#pragma unroll
            for (int k = 0; k < 32; ++k)
                acc = fmaf(wf2r[k],      (float)((lo >> k) & 1u), acc);
#pragma unroll
            for (int k = 0; k < 32; ++k)
                acc = fmaf(wf2r[32 + k], (float)((hi >> k) & 1u), acc);
            mf2 = lif_update(mf2, acc + bf2r);
        }
        const uint64_t sf2 = __ballot((lane < 48) && (mf2 > 1.0f));

        // ---- layer o: full sequential K=48 per lane (16x redundant, free;
        //      preserves single-accumulator ascending-k exactness) ----
        {
            const float* worow = &wo_s[n_o * 48];
            float acc = 0.f;
#pragma unroll
            for (int k = 0; k < 48; ++k)
                acc = fmaf(worow[k], (float)((uint32_t)(sf2 >> k) & 1u), acc);
            mo = lif_update(mo, acc + bor);
            if ((lane & 15) == 0)
                out[base * 4 + n_o] = (mo > 1.0f) ? 1.0f : 0.0f;   // f32 write
        }
    }
}

extern "C" void kernel_launch(void* const* d_in, const int* in_sizes, int n_in,
                              void* d_out, int out_size, void* d_ws, size_t ws_size,
                              hipStream_t stream) {
    const float* left  = (const float*)d_in[0];
    const float* right = (const float*)d_in[1];
    const float* ctx   = (const float*)d_in[2];
    const float* Wl1   = (const float*)d_in[3];
    const float* bl1   = (const float*)d_in[4];
    const float* Wl2   = (const float*)d_in[5];
    const float* bl2   = (const float*)d_in[6];
    const float* Wr1   = (const float*)d_in[7];
    const float* br1   = (const float*)d_in[8];
    const float* Wr2   = (const float*)d_in[9];
    const float* br2   = (const float*)d_in[10];
    const float* Wc    = (const float*)d_in[11];
    const float* bc    = (const float*)d_in[12];
    const float* Wf    = (const float*)d_in[13];
    const float* bf    = (const float*)d_in[14];
    const float* Wf2   = (const float*)d_in[15];
    const float* bf2   = (const float*)d_in[16];
    const float* Wo    = (const float*)d_in[17];
    const float* bo    = (const float*)d_in[18];
    float* out = (float*)d_out;

    hipLaunchKernelGGL(snn_kernel, dim3(BATCH / 4), dim3(256), 0, stream,
                       left, right, ctx, Wl1, bl1, Wl2, bl2, Wr1, br1, Wr2, br2,
                       Wc, bc, Wf, bf, Wf2, bf2, Wo, bo, out);
}